// Round 1
// baseline (253.064 us; speedup 1.0000x reference)
//
#include <hip/hip_runtime.h>
#include <math.h>

#define B_SZ   8192
#define D_IN   2048
#define D_OUT  2048
#define N_NODES 4095
#define STEPS  12          // DEPTH+1

// ---------------------------------------------------------------------------
// Kernel 1: transpose W_out (D_OUT x N_NODES, row-major) -> Wt (N_NODES x D_OUT)
// so phase-3 per-node row reads are contiguous.
// ---------------------------------------------------------------------------
__global__ __launch_bounds__(256) void transpose_wout(
    const float* __restrict__ W, float* __restrict__ Wt) {
  __shared__ float tile[32][33];                 // +1 pad: conflict-free both phases
  const int tx = threadIdx.x;                    // 0..31
  const int ty = threadIdx.y;                    // 0..7
  const int col0 = blockIdx.x * 32;              // along N_NODES
  const int row0 = blockIdx.y * 32;              // along D_OUT (always full: 2048 % 32 == 0)

  #pragma unroll
  for (int i = ty; i < 32; i += 8) {
    const int c = col0 + tx;
    float v = 0.0f;
    if (c < N_NODES) v = W[(size_t)(row0 + i) * N_NODES + c];
    tile[i][tx] = v;
  }
  __syncthreads();
  #pragma unroll
  for (int i = ty; i < 32; i += 8) {
    const int r = col0 + i;                      // along N_NODES
    if (r < N_NODES) Wt[(size_t)r * D_OUT + row0 + tx] = tile[tx][i];
  }
}

// ---------------------------------------------------------------------------
// Kernel 2: routing. One wave (64 lanes) per sample. x row lives in 32 VGPRs
// per lane. 12 sequential (dot -> sign -> child) steps; butterfly shuffle
// reduction gives all lanes the wave-uniform score.
// ---------------------------------------------------------------------------
__global__ __launch_bounds__(256) void route_kernel(
    const float* __restrict__ x, const float* __restrict__ W_in,
    int* __restrict__ nodes, float* __restrict__ gsc) {
  const int wave = (int)((blockIdx.x * (size_t)blockDim.x + threadIdx.x) >> 6);
  const int lane = threadIdx.x & 63;
  if (wave >= B_SZ) return;

  const float* xr = x + (size_t)wave * D_IN;
  float xv[D_IN / 64];
  #pragma unroll
  for (int i = 0; i < D_IN / 64; ++i) xv[i] = xr[lane + i * 64];

  int cur = 0;
  #pragma unroll
  for (int d = 0; d < STEPS; ++d) {
    const float* wr = W_in + (size_t)cur * D_IN;
    float s = 0.0f;
    #pragma unroll
    for (int i = 0; i < D_IN / 64; ++i) s += xv[i] * wr[lane + i * 64];
    // 64-lane butterfly: every lane ends with the full sum (wave-uniform)
    #pragma unroll
    for (int off = 32; off > 0; off >>= 1) s += __shfl_xor(s, off);

    if (lane == 0) {
      nodes[wave * STEPS + d] = cur;
      // exact GELU: 0.5*x*(1+erf(x/sqrt(2)))  (matches approximate=False)
      gsc[wave * STEPS + d] = 0.5f * s * (1.0f + erff(s * 0.70710678118654752f));
    }
    cur = cur * 2 + ((s >= 0.0f) ? 2 : 1);
  }
}

// ---------------------------------------------------------------------------
// Kernel 3: output projection. One 256-thread block per sample. Each thread
// accumulates two float4 chunks (o = 4t .. 4t+3 and o = 1024+4t .. 1024+4t+3).
// ---------------------------------------------------------------------------
__global__ __launch_bounds__(256) void out_kernel(
    const float* __restrict__ Wt, const int* __restrict__ nodes,
    const float* __restrict__ gsc, float* __restrict__ out) {
  const int b = blockIdx.x;
  const int t = threadIdx.x;

  __shared__ int   s_nodes[STEPS];
  __shared__ float s_g[STEPS];
  if (t < STEPS) {
    s_nodes[t] = nodes[b * STEPS + t];
    s_g[t]     = gsc[b * STEPS + t];
  }
  __syncthreads();

  float4 acc0 = make_float4(0.f, 0.f, 0.f, 0.f);
  float4 acc1 = make_float4(0.f, 0.f, 0.f, 0.f);

  #pragma unroll
  for (int d = 0; d < STEPS; ++d) {
    const float4* wr = (const float4*)(Wt + (size_t)s_nodes[d] * D_OUT);
    const float g = s_g[d];
    const float4 w0 = wr[t];
    const float4 w1 = wr[256 + t];
    acc0.x += g * w0.x; acc0.y += g * w0.y; acc0.z += g * w0.z; acc0.w += g * w0.w;
    acc1.x += g * w1.x; acc1.y += g * w1.y; acc1.z += g * w1.z; acc1.w += g * w1.w;
  }

  float4* op = (float4*)(out + (size_t)b * D_OUT);
  op[t]       = acc0;
  op[256 + t] = acc1;
}

// ---------------------------------------------------------------------------
extern "C" void kernel_launch(void* const* d_in, const int* in_sizes, int n_in,
                              void* d_out, int out_size, void* d_ws, size_t ws_size,
                              hipStream_t stream) {
  const float* x     = (const float*)d_in[0];   // (B, D_IN)
  const float* W_in  = (const float*)d_in[1];   // (N_NODES, D_IN)
  const float* W_out = (const float*)d_in[2];   // (D_OUT, N_NODES)
  float* out = (float*)d_out;                   // (B, D_OUT)

  // workspace layout
  float* Wt   = (float*)d_ws;                                    // N_NODES*D_OUT floats
  int*   nodes = (int*)((char*)d_ws + (size_t)N_NODES * D_OUT * sizeof(float));
  float* gsc   = (float*)((char*)nodes + (size_t)B_SZ * STEPS * sizeof(int));

  // 1) transpose W_out -> Wt
  {
    dim3 blk(32, 8);
    dim3 grd((N_NODES + 31) / 32, D_OUT / 32);
    transpose_wout<<<grd, blk, 0, stream>>>(W_out, Wt);
  }
  // 2) routing: one wave/sample, 4 waves per 256-thread block
  {
    dim3 blk(256);
    dim3 grd(B_SZ / 4);
    route_kernel<<<grd, blk, 0, stream>>>(x, W_in, nodes, gsc);
  }
  // 3) output projection: one block/sample
  {
    dim3 blk(256);
    dim3 grd(B_SZ);
    out_kernel<<<grd, blk, 0, stream>>>(Wt, nodes, gsc, out);
  }
}

// Round 2
// 247.733 us; speedup vs baseline: 1.0215x; 1.0215x over previous
//
#include <hip/hip_runtime.h>
#include <math.h>

#define B_SZ    8192
#define D_IN    2048
#define D_OUT   2048
#define N_NODES 4095
#define STEPS   12          // DEPTH+1
#define N_LEAVES 2048       // nodes at depth 11: ids 2047..4094

// ---------------------------------------------------------------------------
// Kernel 1: transpose W_out (D_OUT x N_NODES) -> Wt (N_NODES x D_OUT)
// ---------------------------------------------------------------------------
__global__ __launch_bounds__(256) void transpose_wout(
    const float* __restrict__ W, float* __restrict__ Wt) {
  __shared__ float tile[32][33];
  const int tx = threadIdx.x;       // 0..31
  const int ty = threadIdx.y;       // 0..7
  const int col0 = blockIdx.x * 32; // along N_NODES
  const int row0 = blockIdx.y * 32; // along D_OUT (2048 % 32 == 0)

  #pragma unroll
  for (int i = ty; i < 32; i += 8) {
    const int c = col0 + tx;
    float v = 0.0f;
    if (c < N_NODES) v = W[(size_t)(row0 + i) * N_NODES + c];
    tile[i][tx] = v;
  }
  __syncthreads();
  #pragma unroll
  for (int i = ty; i < 32; i += 8) {
    const int r = col0 + i;
    if (r < N_NODES) Wt[(size_t)r * D_OUT + row0 + tx] = tile[tx][i];
  }
}

// ---------------------------------------------------------------------------
// Kernel 2: routing. One wave per sample; x row in 8 float4/lane; 12 dependent
// (dot -> butterfly-reduce -> sign -> child) steps, float4 vectorized loads.
// Emits gelu(score) per depth and the leaf index (depth-11 node - 2047).
// ---------------------------------------------------------------------------
__global__ __launch_bounds__(256) void route_kernel(
    const float* __restrict__ x, const float* __restrict__ W_in,
    int* __restrict__ leafArr, float* __restrict__ gsc) {
  const int wave = (int)((blockIdx.x * (size_t)blockDim.x + threadIdx.x) >> 6);
  const int lane = threadIdx.x & 63;
  if (wave >= B_SZ) return;

  const float4* xr = (const float4*)(x + (size_t)wave * D_IN);
  float4 xv[8];
  #pragma unroll
  for (int i = 0; i < 8; ++i) xv[i] = xr[lane + i * 64];

  int cur = 0;
  #pragma unroll
  for (int d = 0; d < STEPS; ++d) {
    const float4* wr = (const float4*)(W_in + (size_t)cur * D_IN);
    float s = 0.0f;
    #pragma unroll
    for (int i = 0; i < 8; ++i) {
      const float4 w = wr[lane + i * 64];
      s += xv[i].x * w.x + xv[i].y * w.y + xv[i].z * w.z + xv[i].w * w.w;
    }
    #pragma unroll
    for (int off = 32; off > 0; off >>= 1) s += __shfl_xor(s, off);

    if (lane == 0) {
      // exact GELU (matches approximate=False)
      gsc[wave * STEPS + d] = 0.5f * s * (1.0f + erff(s * 0.70710678118654752f));
      if (d == STEPS - 1) leafArr[wave] = cur - 2047;  // leaf index 0..2047
    }
    cur = cur * 2 + ((s >= 0.0f) ? 2 : 1);
  }
}

// ---------------------------------------------------------------------------
// Kernel 3: output projection, leaf-grouped. One block per leaf. The leaf id
// determines the whole 12-node path (ancestors), so the block loads the 12 Wt
// rows ONCE into registers and emits every sample routed to this leaf.
// Wt traffic: 2048 x 96 KB = 192 MB total (vs 786 MB ungrouped).
// ---------------------------------------------------------------------------
__global__ __launch_bounds__(256) void out_kernel(
    const float* __restrict__ Wt, const int* __restrict__ leafArr,
    const float* __restrict__ gsc, float* __restrict__ out) {
  __shared__ int list[B_SZ];   // worst case: all samples in one leaf
  __shared__ int cnt;
  const int l = blockIdx.x;    // leaf index 0..2047
  const int t = threadIdx.x;

  if (t == 0) cnt = 0;
  __syncthreads();
  for (int b = t; b < B_SZ; b += 256)
    if (leafArr[b] == l) list[atomicAdd(&cnt, 1)] = b;
  __syncthreads();
  const int n = cnt;
  if (n == 0) return;

  // reconstruct path from leaf: node at depth 11 = l + 2047; parent = (nd-1)>>1
  int path[STEPS];
  {
    int nd = l + 2047;
    #pragma unroll
    for (int d = STEPS - 1; d >= 0; --d) { path[d] = nd; nd = (nd - 1) >> 1; }
  }

  #pragma unroll
  for (int c = 0; c < 2; ++c) {
    const int col = c * 1024 + t * 4;
    float4 w[STEPS];
    #pragma unroll
    for (int d = 0; d < STEPS; ++d)
      w[d] = *(const float4*)(Wt + (size_t)path[d] * D_OUT + col);

    for (int s = 0; s < n; ++s) {
      const int b = list[s];
      const float* g = gsc + (size_t)b * STEPS;
      float4 acc = make_float4(0.f, 0.f, 0.f, 0.f);
      #pragma unroll
      for (int d = 0; d < STEPS; ++d) {
        const float gd = g[d];   // same addr across wave -> broadcast, L1-hot
        acc.x += gd * w[d].x; acc.y += gd * w[d].y;
        acc.z += gd * w[d].z; acc.w += gd * w[d].w;
      }
      *(float4*)(out + (size_t)b * D_OUT + col) = acc;
    }
  }
}

// ---------------------------------------------------------------------------
extern "C" void kernel_launch(void* const* d_in, const int* in_sizes, int n_in,
                              void* d_out, int out_size, void* d_ws, size_t ws_size,
                              hipStream_t stream) {
  const float* x     = (const float*)d_in[0];   // (B, D_IN)
  const float* W_in  = (const float*)d_in[1];   // (N_NODES, D_IN)
  const float* W_out = (const float*)d_in[2];   // (D_OUT, N_NODES)
  float* out = (float*)d_out;                   // (B, D_OUT)

  // workspace layout
  float* Wt      = (float*)d_ws;                                   // N_NODES*D_OUT
  int*   leafArr = (int*)((char*)d_ws + (size_t)N_NODES * D_OUT * sizeof(float));
  float* gsc     = (float*)((char*)leafArr + (size_t)B_SZ * sizeof(int));

  {
    dim3 blk(32, 8);
    dim3 grd((N_NODES + 31) / 32, D_OUT / 32);
    transpose_wout<<<grd, blk, 0, stream>>>(W_out, Wt);
  }
  {
    dim3 blk(256);
    dim3 grd(B_SZ / 4);   // one wave per sample, 4 waves/block
    route_kernel<<<grd, blk, 0, stream>>>(x, W_in, leafArr, gsc);
  }
  {
    dim3 blk(256);
    dim3 grd(N_LEAVES);   // one block per leaf
    out_kernel<<<grd, blk, 0, stream>>>(Wt, leafArr, gsc, out);
  }
}